// Round 1
// baseline (571.626 us; speedup 1.0000x reference)
//
#include <hip/hip_runtime.h>
#include <hip/hip_bf16.h>

typedef __bf16 bf16_t;
typedef __bf16 bf16x8 __attribute__((ext_vector_type(8)));
typedef float floatx4 __attribute__((ext_vector_type(4)));

#define M_TOK 8192
#define K_DIM 4096
#define N_OUT 4096
#define NEXP  8
#define LRANK 16
#define KEXT  128
#define SCALING 2.0f

// async 16B global -> LDS. LDS arg is wave-uniform base; HW scatters lane i to base + i*16B.
#define GLOAD_LDS16(g, l) \
    __builtin_amdgcn_global_load_lds((const __attribute__((address_space(1))) void*)(g), \
                                     (__attribute__((address_space(3))) void*)(l), 16, 0, 0)

// ---------------------------------------------------------------- helpers

__device__ __forceinline__ void pack4(bf16_t* dst, float4 v) {
    union { bf16_t h[4]; uint2 u; } t;
    t.h[0] = (bf16_t)v.x; t.h[1] = (bf16_t)v.y;
    t.h[2] = (bf16_t)v.z; t.h[3] = (bf16_t)v.w;
    *(uint2*)dst = t.u;
}

__device__ __forceinline__ void cvt8_body(const float* __restrict__ src,
                                          bf16_t* __restrict__ dst, int blk) {
    size_t i = (size_t)blk * 256 + threadIdx.x;
    float4 a = ((const float4*)src)[i * 2];
    float4 b = ((const float4*)src)[i * 2 + 1];
    union { bf16_t h[8]; uint4 u; } t;
    t.h[0] = (bf16_t)a.x; t.h[1] = (bf16_t)a.y; t.h[2] = (bf16_t)a.z; t.h[3] = (bf16_t)a.w;
    t.h[4] = (bf16_t)b.x; t.h[5] = (bf16_t)b.y; t.h[6] = (bf16_t)b.z; t.h[7] = (bf16_t)b.w;
    ((uint4*)dst)[i] = t.u;
}

// ---------------------------------------------------------------- prep_all: cvt W + cvt loraA + repack loraB

#define PREP_W_BLKS   8192
#define PREP_A_BLKS   256
#define PREP_B_BLKS   2048

__global__ __launch_bounds__(256) void prep_all(const float* __restrict__ W,
                                                const float* __restrict__ loraA,
                                                const float* __restrict__ loraB,
                                                bf16_t* __restrict__ Wb,
                                                bf16_t* __restrict__ aflat,
                                                bf16_t* __restrict__ bflat) {
    int b = blockIdx.x;
    if (b < PREP_W_BLKS) {
        cvt8_body(W, Wb, b);
    } else if (b < PREP_W_BLKS + PREP_A_BLKS) {
        cvt8_body(loraA, aflat, b - PREP_W_BLKS);
    } else {
        int g = (b - PREP_W_BLKS - PREP_A_BLKS) * 256 + threadIdx.x;  // < 4096*128
        int o = g >> 7, j = g & 127;
        int e = j >> 4, r = j & 15;
        bflat[g] = (bf16_t)loraB[((size_t)e * N_OUT + o) * LRANK + r];
    }
}

// ---------------------------------------------------------------- gate_cvt16: router (fp32) + x->bf16

__global__ __launch_bounds__(256) void gate_cvt16(const float* __restrict__ x,
                                                  const float* __restrict__ routeW,
                                                  bf16_t* __restrict__ xb,
                                                  float* __restrict__ rw_out,    // [M,8]
                                                  float* __restrict__ gate_out)  // [M,8]
{
    __shared__ float rwT[NEXP][256];   // 8 KB
    int tid = threadIdx.x, lane = tid & 63, wave = tid >> 6;
    int tl = lane >> 4, seg = lane & 15;
    int t = blockIdx.x * 16 + wave * 4 + tl;
    const float* xrow = x + (size_t)t * K_DIM;
    bf16_t* xbrow = xb + (size_t)t * K_DIM;

    float acc[NEXP];
    #pragma unroll
    for (int e = 0; e < NEXP; ++e) acc[e] = 0.f;

    int srow = tid >> 5, scol = (tid & 31) * 8;

    for (int kk = 0; kk < K_DIM / 256; ++kk) {
        {
            const float4* src = (const float4*)(routeW + (size_t)srow * K_DIM + kk * 256 + scol);
            float4 v0 = src[0], v1 = src[1];
            *(float4*)&rwT[srow][scol]     = v0;
            *(float4*)&rwT[srow][scol + 4] = v1;
        }
        __syncthreads();
        #pragma unroll
        for (int kc = 0; kc < 4; ++kc) {
            int kloc = kc * 64 + seg * 4;
            int k = kk * 256 + kloc;
            float4 xv = *(const float4*)(xrow + k);
            union { bf16_t h[4]; uint2 u; } cv;
            cv.h[0] = (bf16_t)xv.x; cv.h[1] = (bf16_t)xv.y;
            cv.h[2] = (bf16_t)xv.z; cv.h[3] = (bf16_t)xv.w;
            *(uint2*)(xbrow + k) = cv.u;
            #pragma unroll
            for (int e = 0; e < NEXP; ++e) {
                float4 wv = *(const float4*)&rwT[e][kloc];
                acc[e] += xv.x * wv.x + xv.y * wv.y + xv.z * wv.z + xv.w * wv.w;
            }
        }
        __syncthreads();
    }

    #pragma unroll
    for (int e = 0; e < NEXP; ++e) {
        acc[e] += __shfl_xor(acc[e], 1);
        acc[e] += __shfl_xor(acc[e], 2);
        acc[e] += __shfl_xor(acc[e], 4);
        acc[e] += __shfl_xor(acc[e], 8);
    }

    if (seg == 0) {
        float mx = acc[0];
        #pragma unroll
        for (int e = 1; e < NEXP; ++e) mx = fmaxf(mx, acc[e]);
        float p[NEXP], s = 0.f;
        #pragma unroll
        for (int e = 0; e < NEXP; ++e) { p[e] = expf(acc[e] - mx); s += p[e]; }
        float inv_s = 1.0f / s;
        #pragma unroll
        for (int e = 0; e < NEXP; ++e) p[e] *= inv_s;
        int i0 = 0;
        #pragma unroll
        for (int e = 1; e < NEXP; ++e) if (p[e] > p[i0]) i0 = e;
        int i1 = (i0 == 0) ? 1 : 0;
        #pragma unroll
        for (int e = 0; e < NEXP; ++e) { if (e == i0 || e == i1) continue; if (p[e] > p[i1]) i1 = e; }
        float v0 = p[i0], v1 = p[i1];
        float inv = 1.0f / (v0 + v1 + 1e-9f);
        float r[NEXP];
        #pragma unroll
        for (int e = 0; e < NEXP; ++e) r[e] = 0.f;
        r[i0] = v0 * inv; r[i1] = v1 * inv;
        #pragma unroll
        for (int e = 0; e < NEXP; ++e) {
            gate_out[(size_t)t * NEXP + e] = acc[e];
            rw_out[(size_t)t * NEXP + e]  = r[e];
        }
    }
}

// ---------------------------------------------------------------- h_v3 (unchanged)

__global__ __launch_bounds__(256) void h_kernel_v3(const bf16_t* __restrict__ xb,
                                                   const bf16_t* __restrict__ aflat,
                                                   const float* __restrict__ rw,
                                                   bf16_t* __restrict__ hw)
{
    __shared__ bf16_t As[4 * 32 * 32];
    __shared__ bf16_t Bs[4 * 128 * 32];
    int tid = threadIdx.x, lane = tid & 63, wave = tid >> 6;
    int lrow = lane & 15, lq = lane >> 4;
    int n0 = wave * 32;
    int m0 = blockIdx.x * 32;
    floatx4 acc[2][2] = {};

    const bf16_t* srcA[2];
    #pragma unroll
    for (int i = 0; i < 2; ++i) {
        int idx = i * 256 + tid;
        int ks = idx >> 7, r = (idx >> 2) & 31, cc2 = idx & 3;
        srcA[i] = xb + (size_t)(m0 + r) * K_DIM + ks * 32 + cc2 * 8;
    }
    const bf16_t* srcB[8];
    #pragma unroll
    for (int i = 0; i < 8; ++i) {
        int idx = i * 256 + tid;
        int ks = idx >> 9, r = (idx >> 2) & 127, cc2 = idx & 3;
        srcB[i] = aflat + (size_t)r * K_DIM + ks * 32 + cc2 * 8;
    }

    for (int k0 = 0; k0 < K_DIM; k0 += 128) {
        #pragma unroll
        for (int i = 0; i < 2; ++i)
            GLOAD_LDS16(srcA[i] + k0, (char*)As + (i * 256 + wave * 64) * 16);
        #pragma unroll
        for (int i = 0; i < 8; ++i)
            GLOAD_LDS16(srcB[i] + k0, (char*)Bs + (i * 256 + wave * 64) * 16);
        __syncthreads();
        #pragma unroll
        for (int ks = 0; ks < 4; ++ks) {
            bf16x8 af[2], bfr[2];
            #pragma unroll
            for (int mi = 0; mi < 2; ++mi)
                af[mi] = *(const bf16x8*)(As + ks * 1024 + (mi * 16 + lrow) * 32 + lq * 8);
            #pragma unroll
            for (int ni = 0; ni < 2; ++ni)
                bfr[ni] = *(const bf16x8*)(Bs + ks * 4096 + (n0 + ni * 16 + lrow) * 32 + lq * 8);
            #pragma unroll
            for (int mi = 0; mi < 2; ++mi)
                #pragma unroll
                for (int ni = 0; ni < 2; ++ni)
                    acc[mi][ni] = __builtin_amdgcn_mfma_f32_16x16x32_bf16(af[mi], bfr[ni], acc[mi][ni], 0, 0, 0);
        }
        __syncthreads();
    }
    #pragma unroll
    for (int mi = 0; mi < 2; ++mi)
        #pragma unroll
        for (int ni = 0; ni < 2; ++ni)
            #pragma unroll
            for (int reg = 0; reg < 4; ++reg) {
                int t = m0 + mi * 16 + lq * 4 + reg;
                int j = n0 + ni * 16 + lrow;
                float g = rw[(size_t)t * NEXP + (j >> 4)] * SCALING;
                hw[(size_t)t * KEXT + j] = (bf16_t)(acc[mi][ni][reg] * g);
            }
}

// ---------------------------------------------------------------- main GEMM v3: 256x256 tile, BK=64,
// double-buffered LDS (128 KiB), 4-phase schedule per K-tile with counted vmcnt + setprio.
// Prefetch of tile t+1 issued at phases 0-1 of tile t; single vmcnt(0) at phase 3 (~2-3 phases of slack).
// XOR granule swizzle (pg = g ^ (row&7)) applied via pre-swizzled DMA source + swizzled ds_read addr.

#define BM 256
#define BN 256
#define BK 64
#define NT ((K_DIM + KEXT) / BK)   // 66

__global__ __launch_bounds__(512) void main_gemm_v3(const bf16_t* __restrict__ xb,
                                                    const bf16_t* __restrict__ Wb,
                                                    const float* __restrict__ bias,
                                                    const bf16_t* __restrict__ hw,
                                                    const bf16_t* __restrict__ bflat,
                                                    float* __restrict__ out)
{
    __shared__ __align__(16) bf16_t As[2][BM * BK];   // 2 x 32 KB
    __shared__ __align__(16) bf16_t Bs[2][BN * BK];   // 2 x 32 KB
    int tid = threadIdx.x, lane = tid & 63, wave = tid >> 6;   // 8 waves
    int lrow = lane & 15, lq = lane >> 4;
    int wm = (wave >> 2) * 128;   // 2 M-wave-groups
    int wn = (wave & 3) * 64;     // 4 N-wave-groups

    // XCD-aware block swizzle: 512 wgs, divisible by 8 -> simple bijective remap
    int lin = blockIdx.y * gridDim.x + blockIdx.x;
    int swzb = (lin & 7) * 64 + (lin >> 3);
    int tm = (swzb >> 4) * BM;    // 32 M-tiles
    int tn = (swzb & 15) * BN;    // 16 N-tiles

    int swz = lrow & 7;
    int go0 = (lq ^ swz) * 8;          // k-step 0 granule offset (elems)
    int go1 = ((4 + lq) ^ swz) * 8;    // k-step 1

    // staging geometry: linear slot s = j*512 + tid; row = s>>3; phys granule = s&7
    // row & 7 == (tid>>3) & 7 (j*64 multiple of 8) -> lg per-thread constant
    int rb = tid >> 3;                               // 0..63 (+ j*64)
    int lg8 = ((tid & 7) ^ (rb & 7)) * 8;
    size_t oA  = (size_t)(tm + rb) * K_DIM + lg8;
    size_t oB  = (size_t)(tn + rb) * K_DIM + lg8;
    size_t oEA = (size_t)(tm + rb) * KEXT + lg8;
    size_t oEB = (size_t)(tn + rb) * KEXT + lg8;
    char* ldA = (char*)As + wave * 1024;             // + nxt*32768 + j*8192
    char* ldB = (char*)Bs + wave * 1024;

    floatx4 acc[8][4] = {};

    // ---- prologue: stage tile 0 into buffer 0, full drain once
    #pragma unroll
    for (int j = 0; j < 4; ++j) {
        GLOAD_LDS16(xb + oA + (size_t)j * (64 * K_DIM), ldA + j * 8192);
        GLOAD_LDS16(Wb + oB + (size_t)j * (64 * K_DIM), ldB + j * 8192);
    }
    __syncthreads();

    for (int t = 0; t < NT; ++t) {
        int cur = t & 1, nxt = cur ^ 1;
        const bf16_t* curA = &As[cur][(wm + lrow) * BK];
        const bf16_t* curB = &Bs[cur][(wn + lrow) * BK];
        bool pf = (t + 1 < NT);
        int tt = t + 1;

        bf16x8 afA[4][2], afB[4][2], bf0[2][2], bf1[2][2];

        // ================ phase 0: read A(m-half0)+B(n-half0); stage A(t+1); MFMA m0 x n0
        #pragma unroll
        for (int f = 0; f < 4; ++f) {
            afA[f][0] = *(const bf16x8*)(curA + (f * 16) * BK + go0);
            afA[f][1] = *(const bf16x8*)(curA + (f * 16) * BK + go1);
        }
        #pragma unroll
        for (int n = 0; n < 2; ++n) {
            bf0[n][0] = *(const bf16x8*)(curB + (n * 16) * BK + go0);
            bf0[n][1] = *(const bf16x8*)(curB + (n * 16) * BK + go1);
        }
        if (pf) {
            const bf16_t* g; size_t js;
            if (tt < K_DIM / BK) { g = xb + oA + (size_t)tt * BK;                 js = (size_t)64 * K_DIM; }
            else                 { g = hw + oEA + (size_t)(tt - K_DIM / BK) * BK; js = (size_t)64 * KEXT; }
            char* d = ldA + nxt * (BM * BK * 2);
            #pragma unroll
            for (int j = 0; j < 4; ++j) GLOAD_LDS16(g + j * js, d + j * 8192);
        }
        __builtin_amdgcn_s_barrier();
        asm volatile("s_waitcnt lgkmcnt(0)" ::: "memory");
        __builtin_amdgcn_sched_barrier(0);
        __builtin_amdgcn_s_setprio(1);
        #pragma unroll
        for (int f = 0; f < 4; ++f)
            #pragma unroll
            for (int n = 0; n < 2; ++n)
                #pragma unroll
                for (int ks = 0; ks < 2; ++ks)
                    acc[f][n] = __builtin_amdgcn_mfma_f32_16x16x32_bf16(afA[f][ks], bf0[n][ks], acc[f][n], 0, 0, 0);
        __builtin_amdgcn_s_setprio(0);
        __builtin_amdgcn_s_barrier();

        // ================ phase 1: read B(n-half1); stage B(t+1); MFMA m0 x n1
        #pragma unroll
        for (int n = 0; n < 2; ++n) {
            bf1[n][0] = *(const bf16x8*)(curB + ((32 + n * 16)) * BK + go0);
            bf1[n][1] = *(const bf16x8*)(curB + ((32 + n * 16)) * BK + go1);
        }
        if (pf) {
            const bf16_t* g; size_t js;
            if (tt < K_DIM / BK) { g = Wb + oB + (size_t)tt * BK;                     js = (size_t)64 * K_DIM; }
            else                 { g = bflat + oEB + (size_t)(tt - K_DIM / BK) * BK;  js = (size_t)64 * KEXT; }
            char* d = ldB + nxt * (BN * BK * 2);
            #pragma unroll
            for (int j = 0; j < 4; ++j) GLOAD_LDS16(g + j * js, d + j * 8192);
        }
        __builtin_amdgcn_s_barrier();
        asm volatile("s_waitcnt lgkmcnt(0)" ::: "memory");
        __builtin_amdgcn_sched_barrier(0);
        __builtin_amdgcn_s_setprio(1);
        #pragma unroll
        for (int f = 0; f < 4; ++f)
            #pragma unroll
            for (int n = 0; n < 2; ++n)
                #pragma unroll
                for (int ks = 0; ks < 2; ++ks)
                    acc[f][2 + n] = __builtin_amdgcn_mfma_f32_16x16x32_bf16(afA[f][ks], bf1[n][ks], acc[f][2 + n], 0, 0, 0);
        __builtin_amdgcn_s_setprio(0);
        __builtin_amdgcn_s_barrier();

        // ================ phase 2: read A(m-half1); MFMA m1 x n0 (bf0 reused)
        #pragma unroll
        for (int f = 0; f < 4; ++f) {
            afB[f][0] = *(const bf16x8*)(curA + ((64 + f * 16)) * BK + go0);
            afB[f][1] = *(const bf16x8*)(curA + ((64 + f * 16)) * BK + go1);
        }
        __builtin_amdgcn_s_barrier();
        asm volatile("s_waitcnt lgkmcnt(0)" ::: "memory");
        __builtin_amdgcn_sched_barrier(0);
        __builtin_amdgcn_s_setprio(1);
        #pragma unroll
        for (int f = 0; f < 4; ++f)
            #pragma unroll
            for (int n = 0; n < 2; ++n)
                #pragma unroll
                for (int ks = 0; ks < 2; ++ks)
                    acc[4 + f][n] = __builtin_amdgcn_mfma_f32_16x16x32_bf16(afB[f][ks], bf0[n][ks], acc[4 + f][n], 0, 0, 0);
        __builtin_amdgcn_s_setprio(0);
        __builtin_amdgcn_s_barrier();

        // ================ phase 3: counted wait for tile t+1 DMA; MFMA m1 x n1 (afB, bf1 reused)
        if (pf) {
            asm volatile("s_waitcnt vmcnt(0)" ::: "memory");   // only tile t+1's 8 loads outstanding
            __builtin_amdgcn_sched_barrier(0);
        }
        __builtin_amdgcn_s_barrier();
        __builtin_amdgcn_s_setprio(1);
        #pragma unroll
        for (int f = 0; f < 4; ++f)
            #pragma unroll
            for (int n = 0; n < 2; ++n)
                #pragma unroll
                for (int ks = 0; ks < 2; ++ks)
                    acc[4 + f][2 + n] = __builtin_amdgcn_mfma_f32_16x16x32_bf16(afB[f][ks], bf1[n][ks], acc[4 + f][2 + n], 0, 0, 0);
        __builtin_amdgcn_s_setprio(0);
        __builtin_amdgcn_s_barrier();
    }

    // ---- epilogue
    #pragma unroll
    for (int mh = 0; mh < 2; ++mh)
        #pragma unroll
        for (int f = 0; f < 4; ++f)
            #pragma unroll
            for (int nh = 0; nh < 2; ++nh)
                #pragma unroll
                for (int n = 0; n < 2; ++n) {
                    int row = tm + wm + mh * 64 + f * 16 + lq * 4;
                    int col = tn + wn + nh * 32 + n * 16 + lrow;
                    float b = bias[col];
                    #pragma unroll
                    for (int reg = 0; reg < 4; ++reg)
                        out[(size_t)(row + reg) * N_OUT + col] = acc[mh * 4 + f][nh * 2 + n][reg] + b;
                }
}

// ================================================================ FALLBACK PATH (round-1, known-good)

__global__ __launch_bounds__(256) void prep_bflat(const float* __restrict__ loraB,
                                                  bf16_t* __restrict__ bflat) {
    int g = blockIdx.x * 256 + threadIdx.x;
    int o = g >> 7, j = g & 127;
    int e = j >> 4, r = j & 15;
    bflat[g] = (bf16_t)loraB[((size_t)e * N_OUT + o) * LRANK + r];
}

__global__ __launch_bounds__(256) void gate_kernel(const float* __restrict__ x,
                                                   const float* __restrict__ routeW,
                                                   float* __restrict__ rw_out,
                                                   float* __restrict__ gate_out)
{
    int wave = threadIdx.x >> 6;
    int lane = threadIdx.x & 63;
    int t = blockIdx.x * 4 + wave;
    const float4* xp = (const float4*)(x + (size_t)t * K_DIM);
    float acc[NEXP];
    #pragma unroll
    for (int e = 0; e < NEXP; ++e) acc[e] = 0.f;
    #pragma unroll 4
    for (int it = 0; it < K_DIM / 256; ++it) {
        float4 xv = xp[it * 64 + lane];
        #pragma unroll
        for (int e = 0; e < NEXP; ++e) {
            float4 wv = ((const float4*)(routeW + (size_t)e * K_DIM))[it * 64 + lane];
            acc[e] += xv.x * wv.x + xv.y * wv.y + xv.z * wv.z + xv.w * wv.w;
        }
    }
    #pragma unroll
    for (int e = 0; e < NEXP; ++e)
        for (int off = 32; off > 0; off >>= 1)
            acc[e] += __shfl_xor(acc[e], off, 64);
    if (lane == 0) {
        float mx = acc[0];
        #pragma unroll
        for (int e = 1; e < NEXP; ++e) mx = fmaxf(mx, acc[e]);
        float p[NEXP], s = 0.f;
        #pragma unroll
        for (int e = 0; e < NEXP; ++e) { p[e] = expf(acc[e] - mx); s += p[e]; }
        float inv_s = 1.0f / s;
        #pragma unroll
        for (int e = 0; e < NEXP; ++e) p[e] *= inv_s;
        int i0 = 0;
        #pragma unroll
        for (int e = 1; e < NEXP; ++e) if (p[e] > p[i0]) i0 = e;
        int i1 = (i0 == 0) ? 1 : 0;
        #pragma unroll
        for (int e = 0; e < NEXP; ++e) { if (e == i0 || e == i1) continue; if (p[e] > p[i1]) i1 = e; }
        float v0 = p[i0], v1 = p[i1];
        float inv = 1.0f / (v0 + v1 + 1e-9f);
        float r[NEXP];
        #pragma unroll
        for (int e = 0; e < NEXP; ++e) r[e] = 0.f;
        r[i0] = v0 * inv; r[i1] = v1 * inv;
        #pragma unroll
        for (int e = 0; e < NEXP; ++e) {
            gate_out[(size_t)t * NEXP + e] = acc[e];
            rw_out[(size_t)t * NEXP + e]  = r[e];
        }
    }
}

__global__ __launch_bounds__(256) void h_kernel(const float* __restrict__ x,
                                                const float* __restrict__ loraA,
                                                const float* __restrict__ rw,
                                                bf16_t* __restrict__ hw)
{
    __shared__ bf16_t As[32][40];
    __shared__ bf16_t Bs[128][40];
    int tid = threadIdx.x;
    int wave = tid >> 6, lane = tid & 63;
    int lrow = lane & 15, lq = lane >> 4;
    int m0 = blockIdx.x * 32;
    floatx4 acc[2][2] = {};
    int rb = tid >> 1, cb = (tid & 1) * 16;
    for (int k0 = 0; k0 < K_DIM; k0 += 32) {
        if (tid < 64) {
            const float* srcA = x + (size_t)(m0 + rb) * K_DIM + k0 + cb;
            #pragma unroll
            for (int q = 0; q < 4; ++q) pack4(&As[rb][cb + q * 4], ((const float4*)srcA)[q]);
        }
        {
            const float* srcB = loraA + (size_t)rb * K_DIM + k0 + cb;
            #pragma unroll
            for (int q = 0; q < 4; ++q) pack4(&Bs[rb][cb + q * 4], ((const float4*)srcB)[q]);
        }
        __syncthreads();
        bf16x8 af[2], bfr[2];
        #pragma unroll
        for (int mi = 0; mi < 2; ++mi) af[mi] = *(const bf16x8*)&As[mi * 16 + lrow][lq * 8];
        #pragma unroll
        for (int ni = 0; ni < 2; ++ni) bfr[ni] = *(const bf16x8*)&Bs[wave * 32 + ni * 16 + lrow][lq * 8];
        #pragma unroll
        for (int mi = 0; mi < 2; ++mi)
            #pragma unroll
            for (int ni = 0; ni < 2; ++ni)
                acc[mi][ni] = __builtin_amdgcn_mfma_f32_16x16x32_bf16(af[mi], bfr[ni], acc[mi][ni], 0, 0, 0);
        __syncthreads();
    }
    #pragma unroll
    for (int mi = 0; mi < 2; ++mi)
        #pragma unroll
        for (int ni = 0; ni < 2; ++ni)
            #pragma unroll
            for (int reg = 0; reg < 4; ++reg) {
                int t = m0 + mi * 16 + lq * 4 + reg;
                int j = wave * 32 + ni * 16 + lrow;
                float g = rw[(size_t)t * NEXP + (j >> 4)] * SCALING;
                hw[(size_t)t * KEXT + j] = (bf16_t)(acc[mi][ni][reg] * g);
            }
}

__device__ __forceinline__ void mma_step(const bf16_t (*As)[40], const bf16_t (*Bs)[40],
                                         floatx4 acc[4][4], int wm, int wn, int lrow, int lq) {
    bf16x8 af[4], bfr[4];
    #pragma unroll
    for (int mi = 0; mi < 4; ++mi) af[mi] = *(const bf16x8*)&As[wm + mi * 16 + lrow][lq * 8];
    #pragma unroll
    for (int ni = 0; ni < 4; ++ni) bfr[ni] = *(const bf16x8*)&Bs[wn + ni * 16 + lrow][lq * 8];
    #pragma unroll
    for (int mi = 0; mi < 4; ++mi)
        #pragma unroll
        for (int ni = 0; ni < 4; ++ni)
            acc[mi][ni] = __builtin_amdgcn_mfma_f32_16x16x32_bf16(af[mi], bfr[ni], acc[mi][ni], 0, 0, 0);
}

__global__ __launch_bounds__(256) void main_gemm(const float* __restrict__ x,
                                                 const float* __restrict__ W,
                                                 const float* __restrict__ bias,
                                                 const bf16_t* __restrict__ hw,
                                                 const bf16_t* __restrict__ bflat,
                                                 float* __restrict__ out)
{
    __shared__ bf16_t As[128][40];
    __shared__ bf16_t Bs[128][40];
    int tid = threadIdx.x, lane = tid & 63, wave = tid >> 6;
    int lrow = lane & 15, lq = lane >> 4;
    int wm = (wave >> 1) * 64, wn = (wave & 1) * 64;
    int tm = blockIdx.y * 128, tn = blockIdx.x * 128;
    floatx4 acc[4][4] = {};
    int rb = tid >> 1, cb = (tid & 1) * 16;
    const float* gA = x + (size_t)(tm + rb) * K_DIM + cb;
    const float* gB = W + (size_t)(tn + rb) * K_DIM + cb;
    for (int k0 = 0; k0 < K_DIM; k0 += 32) {
        #pragma unroll
        for (int q = 0; q < 4; ++q) {
            pack4(&As[rb][cb + q * 4], ((const float4*)(gA + k0))[q]);
            pack4(&Bs[rb][cb + q * 4], ((const float4*)(gB + k0))[q]);
        }
        __syncthreads();
        mma_step(As, Bs, acc, wm, wn, lrow, lq);
        __syncthreads();
    }
    const bf16_t* eA = hw    + (size_t)(tm + rb) * KEXT + cb;
    const bf16_t* eB = bflat + (size_t)(tn + rb) * KEXT + cb;
    for (int k0 = 0; k0 < KEXT; k0 += 32) {
        *(uint4*)&As[rb][cb]     = *(const uint4*)(eA + k0);
        *(uint4*)&As[rb][cb + 8] = *(const uint4*)(eA + k0 + 8);
        *(uint4*)&Bs[rb][cb]     = *(const uint4*)(eB + k0);
        *(uint4*)&Bs[rb][cb + 8] = *(const uint4*)(eB + k0 + 8);
        __syncthreads();
        mma_step(As, Bs, acc, wm, wn, lrow, lq);
        __syncthreads();
    }
    #pragma unroll
    for (int mi = 0; mi < 4; ++mi)
        #pragma unroll
        for (int ni = 0; ni < 4; ++ni) {
            int row = tm + wm + mi * 16 + lq * 4;
            int col = tn + wn + ni * 16 + lrow;
            float b = bias[col];
            #pragma unroll
            for (int reg = 0; reg < 4; ++reg)
                out[(size_t)(row + reg) * N_OUT + col] = acc[mi][ni][reg] + b;
        }
}

// ---------------------------------------------------------------- launch

extern "C" void kernel_launch(void* const* d_in, const int* in_sizes, int n_in,
                              void* d_out, int out_size, void* d_ws, size_t ws_size,
                              hipStream_t stream) {
    const float* x      = (const float*)d_in[0];
    const float* W      = (const float*)d_in[1];
    const float* bias   = (const float*)d_in[2];
    const float* routeW = (const float*)d_in[3];
    const float* loraA  = (const float*)d_in[4];   // [8][16][4096] == [128][4096]
    const float* loraB  = (const float*)d_in[5];   // [8][4096][16]

    float* out0 = (float*)d_out;
    float* out1 = out0 + (size_t)M_TOK * N_OUT;
    float* out2 = out1 + (size_t)M_TOK * NEXP;

    size_t need = ((size_t)M_TOK * K_DIM + (size_t)N_OUT * K_DIM +
                   (size_t)KEXT * K_DIM + (size_t)N_OUT * KEXT +
                   (size_t)M_TOK * KEXT) * sizeof(bf16_t);

    if (ws_size >= need) {
        bf16_t* xb    = (bf16_t*)d_ws;
        bf16_t* Wb    = xb + (size_t)M_TOK * K_DIM;
        bf16_t* aflat = Wb + (size_t)N_OUT * K_DIM;
        bf16_t* bflat = aflat + (size_t)KEXT * K_DIM;
        bf16_t* hw    = bflat + (size_t)N_OUT * KEXT;

        hipLaunchKernelGGL(prep_all, dim3(PREP_W_BLKS + PREP_A_BLKS + PREP_B_BLKS), dim3(256), 0, stream,
                           W, loraA, loraB, Wb, aflat, bflat);
        hipLaunchKernelGGL(gate_cvt16, dim3(M_TOK / 16), dim3(256), 0, stream, x, routeW, xb, out1, out2);
        hipLaunchKernelGGL(h_kernel_v3, dim3(M_TOK / 32), dim3(256), 0, stream, xb, aflat, out1, hw);
        hipLaunchKernelGGL(main_gemm_v3, dim3(N_OUT / 256, M_TOK / 256), dim3(512), 0, stream,
                           xb, Wb, bias, hw, bflat, out0);
    } else {
        bf16_t* bflat = (bf16_t*)d_ws;
        bf16_t* hw    = bflat + (size_t)N_OUT * KEXT;
        hipLaunchKernelGGL(prep_bflat, dim3((N_OUT * KEXT) / 256), dim3(256), 0, stream, loraB, bflat);
        hipLaunchKernelGGL(gate_kernel, dim3(M_TOK / 4), dim3(256), 0, stream, x, routeW, out1, out2);
        hipLaunchKernelGGL(h_kernel, dim3(M_TOK / 32), dim3(256), 0, stream, x, loraA, out1, hw);
        hipLaunchKernelGGL(main_gemm, dim3(N_OUT / 128, M_TOK / 128), dim3(256), 0, stream,
                           x, W, bias, hw, bflat, out0);
    }
}